// Round 1
// baseline (1294.690 us; speedup 1.0000x reference)
//
#include <hip/hip_runtime.h>
#include <math.h>

#define BATCH   2
#define SEQ     2048
#define DMODEL  1024
#define NHEADS  16
#define DK      64
#define MROWS   (BATCH * SEQ)                       // 4096
#define OUT0_ELEMS ((size_t)BATCH * SEQ * DMODEL)   // 4,194,304

typedef _Float16 f16;
typedef _Float16 f16x8 __attribute__((ext_vector_type(8)));
typedef _Float16 f16x4 __attribute__((ext_vector_type(4)));
typedef float    f32x4 __attribute__((ext_vector_type(4)));

#define MFMA(a,b,c) __builtin_amdgcn_mfma_f32_16x16x32_f16(a,b,c,0,0,0)

// ---------------------------------------------------------------------------
// Cast a 1024x1024 fp32 weight matrix to fp16. grid 1024 x 256 threads.
// ---------------------------------------------------------------------------
__global__ __launch_bounds__(256) void cast_w_kernel(const float* __restrict__ w,
                                                     f16* __restrict__ o)
{
    int i = blockIdx.x * 256 + threadIdx.x;       // 0 .. 262143 (float4 units)
    float4 v = ((const float4*)w)[i];
    f16x4 r = { (f16)v.x, (f16)v.y, (f16)v.z, (f16)v.w };
    ((f16x4*)o)[i] = r;
}

// ---------------------------------------------------------------------------
// Fragment loaders: lane l holds A[row = l&15][k = (l>>4)*8 + j], j=0..7.
// ---------------------------------------------------------------------------
__device__ inline f16x8 load_frag8(const float* p)
{
    float4 lo = *(const float4*)p;
    float4 hi = *(const float4*)(p + 4);
    f16x8 a;
    a[0]=(f16)lo.x; a[1]=(f16)lo.y; a[2]=(f16)lo.z; a[3]=(f16)lo.w;
    a[4]=(f16)hi.x; a[5]=(f16)hi.y; a[6]=(f16)hi.z; a[7]=(f16)hi.w;
    return a;
}
__device__ inline f16x8 load_frag8(const f16* p) { return *(const f16x8*)p; }

// ---------------------------------------------------------------------------
// Projection GEMM: C[m,n] = sum_k A[m,k]*W16[n,k] + bias[n]
// M=4096, N=1024, K=1024. Block: 512 thr = 8 waves (2m x 4n), tile 128x128,
// wave tile 64x32. No LDS: fragments straight from global (L1/L2 resident).
// TRANSV: write V transposed per-head: out[(b*1024 + n)*2048 + s].
// ---------------------------------------------------------------------------
template<typename AT, typename OT, int TRANSV>
__global__ __launch_bounds__(512) void proj_kernel(const AT* __restrict__ A,
                                                   const f16* __restrict__ W16,
                                                   const float* __restrict__ bias,
                                                   OT* __restrict__ out)
{
    const int tid = threadIdx.x;
    const int w  = tid >> 6;
    const int l  = tid & 63;
    const int lr = l & 15;
    const int lg = l >> 4;
    const int m0 = blockIdx.x * 128 + (w >> 2) * 64;
    const int n0 = blockIdx.y * 128 + (w & 3) * 32;

    f32x4 acc[4][2] = {};

    for (int k0 = 0; k0 < DMODEL; k0 += 32) {
        f16x8 af[4], bf[2];
#pragma unroll
        for (int i = 0; i < 4; ++i)
            af[i] = load_frag8(A + (size_t)(m0 + i*16 + lr) * DMODEL + k0 + lg*8);
#pragma unroll
        for (int j = 0; j < 2; ++j)
            bf[j] = *(const f16x8*)(W16 + (size_t)(n0 + j*16 + lr) * DMODEL + k0 + lg*8);
#pragma unroll
        for (int i = 0; i < 4; ++i)
#pragma unroll
            for (int j = 0; j < 2; ++j)
                acc[i][j] = MFMA(af[i], bf[j], acc[i][j]);
    }

    float bj[2];
#pragma unroll
    for (int j = 0; j < 2; ++j) bj[j] = bias[n0 + j*16 + lr];

#pragma unroll
    for (int i = 0; i < 4; ++i) {
#pragma unroll
        for (int j = 0; j < 2; ++j) {
#pragma unroll
            for (int r = 0; r < 4; ++r) {
                // C/D layout: col = lane&15, row = (lane>>4)*4 + reg
                int row = m0 + i*16 + lg*4 + r;
                int col = n0 + j*16 + lr;
                float v = acc[i][j][r] + bj[j];
                if constexpr (TRANSV) {
                    out[((size_t)((row >> 11) * DMODEL + col)) * SEQ + (row & (SEQ-1))] = (OT)v;
                } else {
                    out[(size_t)row * DMODEL + col] = (OT)v;
                }
            }
        }
    }
}

// ---------------------------------------------------------------------------
// Fused attention: per wave: 16 q-rows. Pass 1: QK^T (MFMA) -> online (m,l).
// Pass 2: recompute QK^T, write normalized P fp32 (the required output) once,
// push P through per-wave swizzled LDS into PV MFMA, write ctx fp16.
// Grid: (bh=32, qt=16), 512 thr = 8 waves. bh on blockIdx.x so each head's
// K/V slice pins to one XCD's L2 (round-robin id%8 = bh%8).
// ---------------------------------------------------------------------------
__global__ __launch_bounds__(512) void attn_kernel(const f16* __restrict__ Q16,
                                                   const f16* __restrict__ K16,
                                                   const f16* __restrict__ Vt16,
                                                   float* __restrict__ attnP,
                                                   f16* __restrict__ C16)
{
    __shared__ f16 Ps[8 * 16 * 64];                 // 2 KB per wave, 16 KB total
    const int bh = blockIdx.x;                      // 0..31
    const int qt = blockIdx.y;                      // 0..15
    const int b  = bh >> 4, h = bh & 15;
    const int tid = threadIdx.x;
    const int w  = tid >> 6;
    const int l  = tid & 63;
    const int lr = l & 15;
    const int lg = l >> 4;
    const int q0 = qt * 128 + w * 16;               // wave's q base

    char* ps = (char*)Ps + w * 2048;

    // Q fragments (row = lr, k-chunks kk*32 + lg*8), loaded once
    const f16* qp = Q16 + (size_t)(b*SEQ + q0 + lr) * DMODEL + h*DK + lg*8;
    f16x8 qf0 = *(const f16x8*)qp;
    f16x8 qf1 = *(const f16x8*)(qp + 32);

    const f16* kbase0 = K16 + (size_t)(b*SEQ) * DMODEL + h*DK + lg*8;

    float m_run[4] = { -INFINITY, -INFINITY, -INFINITY, -INFINITY };
    float l_run[4] = { 0.f, 0.f, 0.f, 0.f };

    // ----- pass 1: online row stats -----
    for (int kt = 0; kt < SEQ/64; ++kt) {
        f32x4 s[4] = {};
        const f16* kb = kbase0 + (size_t)(kt*64 + lr) * DMODEL;
#pragma unroll
        for (int j = 0; j < 4; ++j) {
            f16x8 kf0 = *(const f16x8*)(kb + (size_t)j*16*DMODEL);
            f16x8 kf1 = *(const f16x8*)(kb + (size_t)j*16*DMODEL + 32);
            s[j] = MFMA(qf0, kf0, s[j]);
            s[j] = MFMA(qf1, kf1, s[j]);
        }
#pragma unroll
        for (int r = 0; r < 4; ++r) {
            float v0 = s[0][r]*0.125f, v1 = s[1][r]*0.125f;
            float v2 = s[2][r]*0.125f, v3 = s[3][r]*0.125f;
            float mt = fmaxf(fmaxf(v0, v1), fmaxf(v2, v3));
#pragma unroll
            for (int d = 1; d < 16; d <<= 1) mt = fmaxf(mt, __shfl_xor(mt, d));
            float mn = fmaxf(m_run[r], mt);
            float se = __expf(v0-mn) + __expf(v1-mn) + __expf(v2-mn) + __expf(v3-mn);
#pragma unroll
            for (int d = 1; d < 16; d <<= 1) se += __shfl_xor(se, d);
            l_run[r] = l_run[r] * __expf(m_run[r] - mn) + se;
            m_run[r] = mn;
        }
    }
    float inv_l[4];
#pragma unroll
    for (int r = 0; r < 4; ++r) inv_l[r] = 1.0f / l_run[r];

    // ----- pass 2: P write + PV -----
    f32x4 cacc[4] = {};
    const f16* vbase = Vt16 + (size_t)(b*DMODEL + h*DK + lr) * SEQ + lg*8;

    for (int kt = 0; kt < SEQ/64; ++kt) {
        f32x4 s[4] = {};
        const f16* kb = kbase0 + (size_t)(kt*64 + lr) * DMODEL;
#pragma unroll
        for (int j = 0; j < 4; ++j) {
            f16x8 kf0 = *(const f16x8*)(kb + (size_t)j*16*DMODEL);
            f16x8 kf1 = *(const f16x8*)(kb + (size_t)j*16*DMODEL + 32);
            s[j] = MFMA(qf0, kf0, s[j]);
            s[j] = MFMA(qf1, kf1, s[j]);
        }
        // normalized probabilities: global fp32 write + swizzled LDS fp16 write
#pragma unroll
        for (int r = 0; r < 4; ++r) {
            int row = lg*4 + r;                     // local q row (C/D layout)
            float* prow = attnP + ((size_t)bh*SEQ + q0 + row) * SEQ + kt*64;
#pragma unroll
            for (int j = 0; j < 4; ++j) {
                float p = __expf(s[j][r]*0.125f - m_run[r]) * inv_l[r];
                int col = j*16 + lr;
                prow[col] = p;
                int slot = col >> 3;                // 16B slot within row (8 slots)
                *(f16*)(ps + row*128 + (((slot ^ (row & 7)) << 4) | ((col & 7) << 1))) = (f16)p;
            }
        }
        __syncthreads();                            // drain LDS writes (lgkmcnt)

        // P as MFMA A-operand: row = lr, k-chunk = kk*32 + lg*8 (swizzled read)
        f16x8 pa0 = *(const f16x8*)(ps + lr*128 + (((lg    ) ^ (lr & 7)) << 4));
        f16x8 pa1 = *(const f16x8*)(ps + lr*128 + (((4 + lg) ^ (lr & 7)) << 4));

        const f16* vb = vbase + kt*64;
#pragma unroll
        for (int j = 0; j < 4; ++j) {
            f16x8 vf0 = *(const f16x8*)(vb + (size_t)j*16*SEQ);
            f16x8 vf1 = *(const f16x8*)(vb + (size_t)j*16*SEQ + 32);
            cacc[j] = MFMA(pa0, vf0, cacc[j]);
            cacc[j] = MFMA(pa1, vf1, cacc[j]);
        }
        __syncthreads();                            // WAR guard before next tile
    }

    // ctx fp16 epilogue
#pragma unroll
    for (int j = 0; j < 4; ++j)
#pragma unroll
        for (int r = 0; r < 4; ++r) {
            int row = q0 + lg*4 + r;
            int col = h*DK + j*16 + lr;
            C16[(size_t)(b*SEQ + row) * DMODEL + col] = (f16)cacc[j][r];
        }
}

// ---------------------------------------------------------------------------
extern "C" void kernel_launch(void* const* d_in, const int* in_sizes, int n_in,
                              void* d_out, int out_size, void* d_ws, size_t ws_size,
                              hipStream_t stream)
{
    const float* query = (const float*)d_in[0];
    const float* key   = (const float*)d_in[1];
    const float* value = (const float*)d_in[2];
    const float* Wq    = (const float*)d_in[3];
    const float* bq    = (const float*)d_in[4];
    const float* Wk    = (const float*)d_in[5];
    const float* bk    = (const float*)d_in[6];
    const float* Wv    = (const float*)d_in[7];
    const float* bv    = (const float*)d_in[8];
    const float* Wo    = (const float*)d_in[9];
    const float* bo    = (const float*)d_in[10];

    float* out  = (float*)d_out;                    // (B,S,DMODEL) fp32
    float* attn = (float*)d_out + OUT0_ELEMS;       // (B,H,S,S)   fp32

    // workspace: 4x 4Mx f16 (Q,K,Vt,ctx) + 4x 1Mx f16 weights = 40 MB
    f16* Q16  = (f16*)d_ws;
    f16* K16  = Q16  + (size_t)MROWS * DMODEL;
    f16* Vt16 = K16  + (size_t)MROWS * DMODEL;
    f16* C16  = Vt16 + (size_t)MROWS * DMODEL;
    f16* Wq16 = C16  + (size_t)MROWS * DMODEL;
    f16* Wk16 = Wq16 + (size_t)DMODEL * DMODEL;
    f16* Wv16 = Wk16 + (size_t)DMODEL * DMODEL;
    f16* Wo16 = Wv16 + (size_t)DMODEL * DMODEL;

    dim3 tCast(256), gCast(DMODEL * DMODEL / 4 / 256);   // 1024 blocks
    hipLaunchKernelGGL(cast_w_kernel, gCast, tCast, 0, stream, Wq, Wq16);
    hipLaunchKernelGGL(cast_w_kernel, gCast, tCast, 0, stream, Wk, Wk16);
    hipLaunchKernelGGL(cast_w_kernel, gCast, tCast, 0, stream, Wv, Wv16);
    hipLaunchKernelGGL(cast_w_kernel, gCast, tCast, 0, stream, Wo, Wo16);

    dim3 tProj(512), gProj(MROWS / 128, DMODEL / 128);   // (32, 8)
    hipLaunchKernelGGL((proj_kernel<float, f16, 0>), gProj, tProj, 0, stream,
                       query, Wq16, bq, Q16);
    hipLaunchKernelGGL((proj_kernel<float, f16, 0>), gProj, tProj, 0, stream,
                       key, Wk16, bk, K16);
    hipLaunchKernelGGL((proj_kernel<float, f16, 1>), gProj, tProj, 0, stream,
                       value, Wv16, bv, Vt16);

    dim3 tAttn(512), gAttn(BATCH * NHEADS, SEQ / 128);   // (32, 16)
    hipLaunchKernelGGL(attn_kernel, gAttn, tAttn, 0, stream,
                       Q16, K16, Vt16, attn, C16);

    hipLaunchKernelGGL((proj_kernel<f16, float, 0>), gProj, tProj, 0, stream,
                       C16, Wo16, bo, out);
}

// Round 2
// 968.785 us; speedup vs baseline: 1.3364x; 1.3364x over previous
//
#include <hip/hip_runtime.h>
#include <math.h>

#define BATCH   2
#define SEQ     2048
#define DMODEL  1024
#define NHEADS  16
#define DK      64
#define MROWS   (BATCH * SEQ)                       // 4096
#define OUT0_ELEMS ((size_t)BATCH * SEQ * DMODEL)   // 4,194,304

typedef _Float16 f16;
typedef _Float16 f16x8 __attribute__((ext_vector_type(8)));
typedef _Float16 f16x4 __attribute__((ext_vector_type(4)));
typedef float    f32x4 __attribute__((ext_vector_type(4)));

#define MFMA(a,b,c) __builtin_amdgcn_mfma_f32_16x16x32_f16(a,b,c,0,0,0)

// async global->LDS, 16B per lane. dst is wave-uniform base; lane l writes dst + l*16.
__device__ inline void gload16(const void* g, void* l)
{
    __builtin_amdgcn_global_load_lds((const __attribute__((address_space(1))) void*)g,
                                     (__attribute__((address_space(3))) void*)l,
                                     16, 0, 0);
}

// ---------------------------------------------------------------------------
// fp32 -> fp16 cast, float4 per thread. grid = elems/4/256 (sizes divide).
// ---------------------------------------------------------------------------
__global__ __launch_bounds__(256) void cast_f32_f16(const float* __restrict__ w,
                                                    f16* __restrict__ o)
{
    int i = blockIdx.x * 256 + threadIdx.x;
    float4 v = ((const float4*)w)[i];
    f16x4 r = { (f16)v.x, (f16)v.y, (f16)v.z, (f16)v.w };
    ((f16x4*)o)[i] = r;
}

// ---------------------------------------------------------------------------
// Projection GEMM (m97-style): C[m,n] = sum_k A[m,k]*W[n,k] + bias[n]
// A: M x 1024 f16 row-major; W: 1024 x 1024 f16 row-major (i.e. A @ W^T).
// Tile 64x64, BK=64, 256 thr = 4 waves (2m x 2n), wave tile 32x32.
// LDS staged via global_load_lds w=16, XOR-swizzled (pre-swizzled source,
// swizzled ds_read) -> conflict-free-ish ds_read_b128.
// Grid (M/64, N/64) = (64,16) = 1024 blocks -> 4 blocks/CU.
// TRANSV: write transposed per-(b,head-dim): out[(b*1024 + n)*2048 + s].
// ---------------------------------------------------------------------------
template<typename OT, int TRANSV>
__global__ __launch_bounds__(256) void gemm_tn(const f16* __restrict__ A,
                                               const f16* __restrict__ W16,
                                               const float* __restrict__ bias,
                                               OT* __restrict__ out)
{
    __shared__ f16 As[64 * 64];    // 8 KB, rows of 128 B (8 x 16B slots)
    __shared__ f16 Bs[64 * 64];    // 8 KB

    const int tid = threadIdx.x;
    const int w  = tid >> 6;
    const int l  = tid & 63;
    const int lr = l & 15;
    const int lg = l >> 4;
    const int m0 = blockIdx.x * 64;
    const int n0 = blockIdx.y * 64;
    const int wm = (w >> 1) * 32;
    const int wn = (w & 1) * 32;

    // staging map: LDS linear byte o = it*4096 + tid*16 ; row = o>>7,
    // phys slot = (o>>4)&7. Source must hold logical slot = phys ^ (row&7).
    int srow[2], scol[2];
#pragma unroll
    for (int it = 0; it < 2; ++it) {
        int o = it * 4096 + tid * 16;
        int row = o >> 7;
        int slot = ((o >> 4) & 7) ^ (row & 7);
        srow[it] = row;
        scol[it] = slot * 8;
    }

    f32x4 acc[2][2] = {};

    for (int k0 = 0; k0 < DMODEL; k0 += 64) {
#pragma unroll
        for (int it = 0; it < 2; ++it) {
            gload16(A   + (size_t)(m0 + srow[it]) * DMODEL + k0 + scol[it],
                    (char*)As + it * 4096 + w * 1024);
            gload16(W16 + (size_t)(n0 + srow[it]) * DMODEL + k0 + scol[it],
                    (char*)Bs + it * 4096 + w * 1024);
        }
        __syncthreads();   // vmcnt(0) drain + barrier (m97 pattern)

        f16x8 af[2][2], bf[2][2];
#pragma unroll
        for (int kk = 0; kk < 2; ++kk)
#pragma unroll
            for (int i = 0; i < 2; ++i) {
                // row&7 == lr&7 (wm, i*16 are multiples of 8)
                af[kk][i] = *(const f16x8*)((char*)As + (wm + i*16 + lr) * 128
                                            + (((kk*4 + lg) ^ (lr & 7)) << 4));
                bf[kk][i] = *(const f16x8*)((char*)Bs + (wn + i*16 + lr) * 128
                                            + (((kk*4 + lg) ^ (lr & 7)) << 4));
            }
#pragma unroll
        for (int kk = 0; kk < 2; ++kk)
#pragma unroll
            for (int i = 0; i < 2; ++i)
#pragma unroll
                for (int j = 0; j < 2; ++j)
                    acc[i][j] = MFMA(af[kk][i], bf[kk][j], acc[i][j]);
        __syncthreads();
    }

    float bv_[2];
#pragma unroll
    for (int j = 0; j < 2; ++j) bv_[j] = bias[n0 + wn + j*16 + lr];

#pragma unroll
    for (int i = 0; i < 2; ++i)
#pragma unroll
        for (int j = 0; j < 2; ++j)
#pragma unroll
            for (int r = 0; r < 4; ++r) {
                int row = m0 + wm + i*16 + lg*4 + r;   // C/D: col=lane&15, row=lg*4+reg
                int col = n0 + wn + j*16 + lr;
                float v = acc[i][j][r] + bv_[j];
                if constexpr (TRANSV)
                    out[((size_t)((row >> 11) * DMODEL + col)) * SEQ + (row & (SEQ-1))] = (OT)v;
                else
                    out[(size_t)row * DMODEL + col] = (OT)v;
            }
}

// ---------------------------------------------------------------------------
// Fused attention, barrier-free. Per wave: 16 q-rows, private 2KB LDS slice.
// Swapped QK^T: s = mfma(K,Q) -> lane (lr,lg) holds P[q=lr][k=j*16+lg*4+r]:
//   - row stats are in-lane (15 ops) + 2 shuffles (xor 16,32)
//   - P store is 4x float4 per lane (vs 16 scalar)
// Pass 1: online (m,l). Pass 2: recompute, write normalized P once (fp32),
// LDS round-trip (XOR-swizzled) -> PV MFMA. No __syncthreads anywhere.
// ---------------------------------------------------------------------------
__global__ __launch_bounds__(512) void attn_kernel(const f16* __restrict__ Q16,
                                                   const f16* __restrict__ K16,
                                                   const f16* __restrict__ Vt16,
                                                   float* __restrict__ attnP,
                                                   f16* __restrict__ C16)
{
    __shared__ f16 Ps[8 * 1024];                    // 2 KB per wave, private
    const int bh = blockIdx.x;                      // 0..31 (same-bh blocks share XCD)
    const int qt = blockIdx.y;                      // 0..15
    const int b  = bh >> 4, h = bh & 15;
    const int tid = threadIdx.x;
    const int w  = tid >> 6;
    const int l  = tid & 63;
    const int lr = l & 15;
    const int lg = l >> 4;
    const int q0 = qt * 128 + w * 16;

    char* ps = (char*)Ps + w * 2048;

    const f16* qp = Q16 + (size_t)(b*SEQ + q0 + lr) * DMODEL + h*DK + lg*8;
    f16x8 qf0 = *(const f16x8*)qp;
    f16x8 qf1 = *(const f16x8*)(qp + 32);

    const f16* kbase0 = K16 + (size_t)(b*SEQ) * DMODEL + h*DK + lg*8;

    // ----- pass 1: online row stats (m,l in RAW score units; scale in exp) -----
    float m_run = -INFINITY, l_run = 0.f;
    for (int kt = 0; kt < SEQ/64; ++kt) {
        f32x4 s[4] = {};
        const f16* kb = kbase0 + (size_t)(kt*64 + lr) * DMODEL;
#pragma unroll
        for (int j = 0; j < 4; ++j) {
            f16x8 kf0 = *(const f16x8*)(kb + (size_t)j*16*DMODEL);
            f16x8 kf1 = *(const f16x8*)(kb + (size_t)j*16*DMODEL + 32);
            s[j] = MFMA(kf0, qf0, s[j]);
            s[j] = MFMA(kf1, qf1, s[j]);
        }
        float mt = s[0][0];
#pragma unroll
        for (int j = 0; j < 4; ++j)
#pragma unroll
            for (int r = 0; r < 4; ++r) mt = fmaxf(mt, s[j][r]);
        mt = fmaxf(mt, __shfl_xor(mt, 16));
        mt = fmaxf(mt, __shfl_xor(mt, 32));
        float mn = fmaxf(m_run, mt);
        float se = 0.f;
#pragma unroll
        for (int j = 0; j < 4; ++j)
#pragma unroll
            for (int r = 0; r < 4; ++r) se += __expf((s[j][r] - mn) * 0.125f);
        se += __shfl_xor(se, 16);
        se += __shfl_xor(se, 32);
        l_run = l_run * __expf((m_run - mn) * 0.125f) + se;
        m_run = mn;
    }
    const float inv_l = 1.0f / l_run;

    // ----- pass 2: normalized P write + PV -----
    f32x4 cacc[4] = {};
    const f16* vbase = Vt16 + (size_t)(b*DMODEL + h*DK + lr) * SEQ + lg*8;
    float* prow = attnP + ((size_t)bh*SEQ + q0 + lr) * SEQ;

    for (int kt = 0; kt < SEQ/64; ++kt) {
        f32x4 s[4] = {};
        const f16* kb = kbase0 + (size_t)(kt*64 + lr) * DMODEL;
#pragma unroll
        for (int j = 0; j < 4; ++j) {
            f16x8 kf0 = *(const f16x8*)(kb + (size_t)j*16*DMODEL);
            f16x8 kf1 = *(const f16x8*)(kb + (size_t)j*16*DMODEL + 32);
            s[j] = MFMA(kf0, qf0, s[j]);
            s[j] = MFMA(kf1, qf1, s[j]);
        }
#pragma unroll
        for (int j = 0; j < 4; ++j) {
            f32x4 p;
#pragma unroll
            for (int r = 0; r < 4; ++r)
                p[r] = __expf((s[j][r] - m_run) * 0.125f) * inv_l;
            // contiguous 4 k's: k = kt*64 + j*16 + lg*4 + r
            *(float4*)(prow + kt*64 + j*16 + lg*4) = *(const float4*)&p;
            // LDS fp16 copy for PV (16B-slot XOR swizzle on row lr)
            f16x4 ph = { (f16)p[0], (f16)p[1], (f16)p[2], (f16)p[3] };
            *(f16x4*)(ps + lr*128
                      + ((((j*2 + (lg >> 1)) ^ (lr & 7)) << 4) | ((lg & 1) << 3))) = ph;
        }
        // intra-wave LDS write->read fence (rule #18)
        asm volatile("s_waitcnt lgkmcnt(0)" ::: "memory");
        __builtin_amdgcn_sched_barrier(0);

        f16x8 pa0 = *(const f16x8*)(ps + lr*128 + (((lg    ) ^ (lr & 7)) << 4));
        f16x8 pa1 = *(const f16x8*)(ps + lr*128 + (((4 + lg) ^ (lr & 7)) << 4));

        const f16* vb = vbase + kt*64;
#pragma unroll
        for (int j = 0; j < 4; ++j) {
            f16x8 vf0 = *(const f16x8*)(vb + (size_t)j*16*SEQ);
            f16x8 vf1 = *(const f16x8*)(vb + (size_t)j*16*SEQ + 32);
            cacc[j] = MFMA(pa0, vf0, cacc[j]);
            cacc[j] = MFMA(pa1, vf1, cacc[j]);
        }
    }

#pragma unroll
    for (int j = 0; j < 4; ++j)
#pragma unroll
        for (int r = 0; r < 4; ++r) {
            int row = q0 + lg*4 + r;
            int col = h*DK + j*16 + lr;
            C16[(size_t)(b*SEQ + row) * DMODEL + col] = (f16)cacc[j][r];
        }
}

// ---------------------------------------------------------------------------
extern "C" void kernel_launch(void* const* d_in, const int* in_sizes, int n_in,
                              void* d_out, int out_size, void* d_ws, size_t ws_size,
                              hipStream_t stream)
{
    const float* query = (const float*)d_in[0];
    const float* key   = (const float*)d_in[1];
    const float* value = (const float*)d_in[2];
    const float* Wq    = (const float*)d_in[3];
    const float* bq    = (const float*)d_in[4];
    const float* Wk    = (const float*)d_in[5];
    const float* bk    = (const float*)d_in[6];
    const float* Wv    = (const float*)d_in[7];
    const float* bv    = (const float*)d_in[8];
    const float* Wo    = (const float*)d_in[9];
    const float* bo    = (const float*)d_in[10];

    float* out  = (float*)d_out;                    // (B,S,DMODEL) fp32
    float* attn = (float*)d_out + OUT0_ELEMS;       // (B,H,S,S)   fp32

    // workspace layout (f16): 4x 4M (Q,K,Vt,ctx) + 4x 1M (weights) + 3x 4M (inputs) = 64 MB
    f16* Q16  = (f16*)d_ws;
    f16* K16  = Q16  + (size_t)MROWS * DMODEL;
    f16* Vt16 = K16  + (size_t)MROWS * DMODEL;
    f16* C16  = Vt16 + (size_t)MROWS * DMODEL;
    f16* Wq16 = C16  + (size_t)MROWS * DMODEL;
    f16* Wk16 = Wq16 + (size_t)DMODEL * DMODEL;
    f16* Wv16 = Wk16 + (size_t)DMODEL * DMODEL;
    f16* Wo16 = Wv16 + (size_t)DMODEL * DMODEL;
    f16* Xq   = Wo16 + (size_t)DMODEL * DMODEL;
    f16* Xk   = Xq   + (size_t)MROWS * DMODEL;
    f16* Xv   = Xk   + (size_t)MROWS * DMODEL;

    dim3 t256(256);
    hipLaunchKernelGGL(cast_f32_f16, dim3(1024), t256, 0, stream, Wq, Wq16);
    hipLaunchKernelGGL(cast_f32_f16, dim3(1024), t256, 0, stream, Wk, Wk16);
    hipLaunchKernelGGL(cast_f32_f16, dim3(1024), t256, 0, stream, Wv, Wv16);
    hipLaunchKernelGGL(cast_f32_f16, dim3(1024), t256, 0, stream, Wo, Wo16);
    hipLaunchKernelGGL(cast_f32_f16, dim3(4096), t256, 0, stream, query, Xq);
    hipLaunchKernelGGL(cast_f32_f16, dim3(4096), t256, 0, stream, key,   Xk);
    hipLaunchKernelGGL(cast_f32_f16, dim3(4096), t256, 0, stream, value, Xv);

    dim3 gProj(MROWS / 64, DMODEL / 64);            // (64,16) = 1024 blocks
    hipLaunchKernelGGL((gemm_tn<f16, 0>),  gProj, t256, 0, stream, Xq, Wq16, bq, Q16);
    hipLaunchKernelGGL((gemm_tn<f16, 0>),  gProj, t256, 0, stream, Xk, Wk16, bk, K16);
    hipLaunchKernelGGL((gemm_tn<f16, 1>),  gProj, t256, 0, stream, Xv, Wv16, bv, Vt16);

    dim3 tAttn(512), gAttn(BATCH * NHEADS, SEQ / 128);   // (32,16)
    hipLaunchKernelGGL(attn_kernel, gAttn, tAttn, 0, stream, Q16, K16, Vt16, attn, C16);

    hipLaunchKernelGGL((gemm_tn<float, 0>), gProj, t256, 0, stream, C16, Wo16, bo, out);
}

// Round 4
// 952.942 us; speedup vs baseline: 1.3586x; 1.0166x over previous
//
#include <hip/hip_runtime.h>
#include <math.h>

#define BATCH   2
#define SEQ     2048
#define DMODEL  1024
#define NHEADS  16
#define DK      64
#define MROWS   (BATCH * SEQ)                       // 4096
#define OUT0_ELEMS ((size_t)BATCH * SEQ * DMODEL)   // 4,194,304

typedef _Float16 f16;
typedef _Float16 f16x8 __attribute__((ext_vector_type(8)));
typedef _Float16 f16x4 __attribute__((ext_vector_type(4)));
typedef float    f32x4 __attribute__((ext_vector_type(4)));

#define MFMA(a,b,c) __builtin_amdgcn_mfma_f32_16x16x32_f16(a,b,c,0,0,0)

__device__ inline void gload16(const void* g, void* l)
{
    __builtin_amdgcn_global_load_lds((const __attribute__((address_space(1))) void*)g,
                                     (__attribute__((address_space(3))) void*)l,
                                     16, 0, 0);
}

// ---------------------------------------------------------------------------
// fp32 -> fp16 cast, float4 per thread.
// ---------------------------------------------------------------------------
__global__ __launch_bounds__(256) void cast_f32_f16(const float* __restrict__ w,
                                                    f16* __restrict__ o)
{
    int i = blockIdx.x * 256 + threadIdx.x;
    float4 v = ((const float4*)w)[i];
    f16x4 r = { (f16)v.x, (f16)v.y, (f16)v.z, (f16)v.w };
    ((f16x4*)o)[i] = r;
}

// ---------------------------------------------------------------------------
// 128x128-tile GEMM (m97 structure): C[m,n] = sum_k A[m,k]*W[n,k] + bias[n]
// A: M x 1024 f16; W: 1024 x 1024 f16 (A @ W^T). BK=64, 512 thr = 8 waves
// (2m x 4n), wave tile 64x32. Swizzled global_load_lds staging (w=16).
// f16 out: LDS-repacked coalesced f16x8 stores. f32 out: direct (64B spans).
// ---------------------------------------------------------------------------
template<typename OT>
__global__ __launch_bounds__(512) void gemm128(const f16* __restrict__ A,
                                               const f16* __restrict__ W16,
                                               const float* __restrict__ bias,
                                               OT* __restrict__ out)
{
    __shared__ __align__(16) char lds[32768];
    f16* As = (f16*)lds;            // 16 KB: 128 rows x 128 B
    f16* Bs = (f16*)(lds + 16384);  // 16 KB

    const int tid = threadIdx.x;
    const int w  = tid >> 6;
    const int l  = tid & 63;
    const int lr = l & 15;
    const int lg = l >> 4;
    const int m0 = blockIdx.x * 128;
    const int n0 = blockIdx.y * 128;
    const int wm = (w >> 2) * 64;
    const int wn = (w & 3) * 32;

    // staging map: LDS linear byte o = it*8192 + tid*16; row = o>>7,
    // phys slot = (o>>4)&7; source holds logical slot = phys ^ (row&7).
    int srow[2], scol[2];
#pragma unroll
    for (int it = 0; it < 2; ++it) {
        int o = it * 8192 + tid * 16;
        int row = o >> 7;
        int slot = ((o >> 4) & 7) ^ (row & 7);
        srow[it] = row;
        scol[it] = slot * 8;
    }

    f32x4 acc[4][2] = {};

    for (int k0 = 0; k0 < DMODEL; k0 += 64) {
#pragma unroll
        for (int it = 0; it < 2; ++it) {
            gload16(A   + (size_t)(m0 + srow[it]) * DMODEL + k0 + scol[it],
                    (char*)As + it * 8192 + w * 1024);
            gload16(W16 + (size_t)(n0 + srow[it]) * DMODEL + k0 + scol[it],
                    (char*)Bs + it * 8192 + w * 1024);
        }
        __syncthreads();

        f16x8 af[2][4], bf[2][2];
#pragma unroll
        for (int kk = 0; kk < 2; ++kk) {
#pragma unroll
            for (int i = 0; i < 4; ++i)
                af[kk][i] = *(const f16x8*)((char*)As + (wm + i*16 + lr) * 128
                                            + (((kk*4 + lg) ^ (lr & 7)) << 4));
#pragma unroll
            for (int j = 0; j < 2; ++j)
                bf[kk][j] = *(const f16x8*)((char*)Bs + (wn + j*16 + lr) * 128
                                            + (((kk*4 + lg) ^ (lr & 7)) << 4));
        }
#pragma unroll
        for (int kk = 0; kk < 2; ++kk)
#pragma unroll
            for (int i = 0; i < 4; ++i)
#pragma unroll
                for (int j = 0; j < 2; ++j)
                    acc[i][j] = MFMA(af[kk][i], bf[kk][j], acc[i][j]);
        __syncthreads();
    }

    float bv_[2];
#pragma unroll
    for (int j = 0; j < 2; ++j) bv_[j] = bias[n0 + wn + j*16 + lr];

    if constexpr (sizeof(OT) == 2) {
        // repack through LDS (reuse staging buffer), coalesced f16x8 stores
        f16* Cs = (f16*)lds;        // 128 x 128 f16 = 32 KB
#pragma unroll
        for (int i = 0; i < 4; ++i)
#pragma unroll
            for (int j = 0; j < 2; ++j)
#pragma unroll
                for (int r = 0; r < 4; ++r)
                    Cs[(wm + i*16 + lg*4 + r) * 128 + wn + j*16 + lr] =
                        (f16)(acc[i][j][r] + bv_[j]);
        __syncthreads();
#pragma unroll
        for (int p = 0; p < 4; ++p) {
            int row = p*32 + (tid >> 4);
            int c   = (tid & 15) * 8;
            *(f16x8*)((f16*)out + (size_t)(m0 + row) * DMODEL + n0 + c) =
                *(const f16x8*)&Cs[row * 128 + c];
        }
    } else {
#pragma unroll
        for (int i = 0; i < 4; ++i)
#pragma unroll
            for (int j = 0; j < 2; ++j)
#pragma unroll
                for (int r = 0; r < 4; ++r)
                    out[(size_t)(m0 + wm + i*16 + lg*4 + r) * DMODEL
                        + n0 + wn + j*16 + lr] = acc[i][j][r] + bv_[j];
    }
}

// ---------------------------------------------------------------------------
// V transpose: Vt[(b*1024 + d)*2048 + s] = V[(b*2048 + s)*1024 + d].
// 64x64 f16 tiles via padded LDS; coalesced 16B loads and stores.
// Grid: (B*SEQ/64, DMODEL/64) = (64,16), 256 threads.
// ---------------------------------------------------------------------------
__global__ __launch_bounds__(256) void transpose_v(const f16* __restrict__ V,
                                                   f16* __restrict__ Vt)
{
    __shared__ f16 T[64][68];
    const int bx = blockIdx.x;
    const int b  = bx >> 5;
    const int s0 = (bx & 31) * 64;
    const int d0 = blockIdx.y * 64;
    const int tid = threadIdx.x;

#pragma unroll
    for (int p = 0; p < 2; ++p) {
        int s = p*32 + (tid >> 3);
        int c = (tid & 7) * 8;
        *(f16x8*)&T[s][c] = *(const f16x8*)(V + (size_t)(b*SEQ + s0 + s) * DMODEL + d0 + c);
    }
    __syncthreads();
#pragma unroll
    for (int p = 0; p < 2; ++p) {
        int d  = p*32 + (tid >> 3);
        int sc = (tid & 7) * 8;
        f16x8 v;
#pragma unroll
        for (int e = 0; e < 8; ++e) v[e] = T[sc + e][d];
        *(f16x8*)(Vt + (size_t)(b*DMODEL + d0 + d) * SEQ + s0 + sc) = v;
    }
}

// ---------------------------------------------------------------------------
// Fused attention. 256 thr = 4 waves, 16 q-rows/wave, grid (bh=32, qt=32).
// Swapped QK^T (lane owns P[q=lr][k=j*16+lg*4+r]). Two passes; pass 2 writes
// normalized P once (nontemporal) + PV via private swizzled LDS.
// VMEM ordering per iter: K[kt+1] prefetch, V[kt] loads, ... stores LAST ->
// no s_waitcnt ever forces store retirement (stores drain with >=1 iter slack).
// ---------------------------------------------------------------------------
#define LOADK(B0, B1, ktv) do {                                                 \
    const f16* kp_ = kbase0 + (size_t)((ktv)*64 + lr) * DMODEL;                 \
    _Pragma("unroll")                                                           \
    for (int j_ = 0; j_ < 4; ++j_) {                                            \
        B0[j_] = *(const f16x8*)(kp_ + (size_t)j_*16*DMODEL);                   \
        B1[j_] = *(const f16x8*)(kp_ + (size_t)j_*16*DMODEL + 32);              \
    } } while (0)

#define QK(B0, B1, s) do {                                                      \
    _Pragma("unroll")                                                           \
    for (int j_ = 0; j_ < 4; ++j_) {                                            \
        s[j_] = MFMA(B0[j_], qf0, s[j_]);                                       \
        s[j_] = MFMA(B1[j_], qf1, s[j_]);                                       \
    } } while (0)

#define P1BODY(C0, C1, N0, N1, ktv, PREF) do {                                  \
    if (PREF) LOADK(N0, N1, (ktv)+1);                                           \
    f32x4 s[4] = {};                                                            \
    QK(C0, C1, s);                                                              \
    float mt = s[0][0];                                                         \
    _Pragma("unroll")                                                           \
    for (int j_ = 0; j_ < 4; ++j_)                                              \
        _Pragma("unroll")                                                       \
        for (int r_ = 0; r_ < 4; ++r_) mt = fmaxf(mt, s[j_][r_]);               \
    mt = fmaxf(mt, __shfl_xor(mt, 16));                                         \
    mt = fmaxf(mt, __shfl_xor(mt, 32));                                         \
    float mn = fmaxf(m_run, mt);                                                \
    float mo_ = -mn * 0.125f;                                                   \
    float se = 0.f;                                                             \
    _Pragma("unroll")                                                           \
    for (int j_ = 0; j_ < 4; ++j_)                                              \
        _Pragma("unroll")                                                       \
        for (int r_ = 0; r_ < 4; ++r_) se += __expf(fmaf(s[j_][r_], 0.125f, mo_)); \
    se += __shfl_xor(se, 16);                                                   \
    se += __shfl_xor(se, 32);                                                   \
    l_run = l_run * __expf((m_run - mn) * 0.125f) + se;                         \
    m_run = mn;                                                                 \
    } while (0)

#define P2BODY(C0, C1, N0, N1, ktv, PREF) do {                                  \
    if (PREF) LOADK(N0, N1, (ktv)+1);                                           \
    f16x8 vf0[4], vf1[4];                                                       \
    {   const f16* vb_ = vbase + (ktv)*64;                                      \
        _Pragma("unroll")                                                       \
        for (int j_ = 0; j_ < 4; ++j_) {                                        \
            vf0[j_] = *(const f16x8*)(vb_ + (size_t)j_*16*SEQ);                 \
            vf1[j_] = *(const f16x8*)(vb_ + (size_t)j_*16*SEQ + 32);            \
        } }                                                                     \
    f32x4 s[4] = {};                                                            \
    QK(C0, C1, s);                                                              \
    _Pragma("unroll")                                                           \
    for (int j_ = 0; j_ < 4; ++j_) {                                            \
        f32x4 p_;                                                               \
        _Pragma("unroll")                                                       \
        for (int r_ = 0; r_ < 4; ++r_)                                          \
            p_[r_] = __expf(fmaf(s[j_][r_], 0.125f, poff));                     \
        __builtin_nontemporal_store(p_,                                         \
            (f32x4*)(prow + (ktv)*64 + j_*16 + lg*4));                          \
        f16x4 ph_ = { (f16)p_[0], (f16)p_[1], (f16)p_[2], (f16)p_[3] };         \
        *(f16x4*)(ps + lr*128                                                   \
            + ((((j_*2 + (lg >> 1)) ^ (lr & 7)) << 4) | ((lg & 1) << 3))) = ph_; \
    }                                                                           \
    asm volatile("s_waitcnt lgkmcnt(0)" ::: "memory");                          \
    __builtin_amdgcn_sched_barrier(0);                                          \
    {   f16x8 pa0_ = *(const f16x8*)(ps + lr*128 + (((lg    ) ^ (lr & 7)) << 4)); \
        f16x8 pa1_ = *(const f16x8*)(ps + lr*128 + (((4 + lg) ^ (lr & 7)) << 4)); \
        _Pragma("unroll")                                                       \
        for (int j_ = 0; j_ < 4; ++j_) {                                        \
            cacc[j_] = MFMA(pa0_, vf0[j_], cacc[j_]);                           \
            cacc[j_] = MFMA(pa1_, vf1[j_], cacc[j_]);                           \
        } }                                                                     \
    } while (0)

__global__ __launch_bounds__(256, 3) void attn_kernel(const f16* __restrict__ Q16,
                                                      const f16* __restrict__ K16,
                                                      const f16* __restrict__ Vt16,
                                                      float* __restrict__ attnP,
                                                      f16* __restrict__ C16)
{
    __shared__ f16 Ps[4 * 1024];                    // 2 KB per wave, private
    const int bh = blockIdx.x;                      // 0..31 -> XCD = bh % 8
    const int qt = blockIdx.y;                      // 0..31
    const int b  = bh >> 4, h = bh & 15;
    const int tid = threadIdx.x;
    const int w  = tid >> 6;
    const int l  = tid & 63;
    const int lr = l & 15;
    const int lg = l >> 4;
    const int q0 = qt * 64 + w * 16;

    char* ps = (char*)Ps + w * 2048;

    const f16* qp = Q16 + (size_t)(b*SEQ + q0 + lr) * DMODEL + h*DK + lg*8;
    f16x8 qf0 = *(const f16x8*)qp;
    f16x8 qf1 = *(const f16x8*)(qp + 32);

    const f16* kbase0 = K16 + (size_t)(b*SEQ) * DMODEL + h*DK + lg*8;
    const f16* vbase  = Vt16 + (size_t)(b*DMODEL + h*DK + lr) * SEQ + lg*8;

    f16x8 kA0[4], kA1[4], kB0[4], kB1[4];

    // ----- pass 1: online row stats -----
    float m_run = -INFINITY, l_run = 0.f;
    LOADK(kA0, kA1, 0);
    for (int kt = 0; kt < 30; kt += 2) {
        P1BODY(kA0, kA1, kB0, kB1, kt,   1);
        P1BODY(kB0, kB1, kA0, kA1, kt+1, 1);
    }
    P1BODY(kA0, kA1, kB0, kB1, 30, 1);
    P1BODY(kB0, kB1, kA0, kA1, 31, 0);

    // p = exp(s*0.125 + poff), poff = -m*0.125 - ln(l)
    const float poff = fmaf(m_run, -0.125f, -logf(l_run));

    // ----- pass 2: normalized P write + PV -----
    f32x4 cacc[4] = {};
    float* prow = attnP + ((size_t)bh*SEQ + q0 + lr) * SEQ;

    LOADK(kA0, kA1, 0);
    for (int kt = 0; kt < 30; kt += 2) {
        P2BODY(kA0, kA1, kB0, kB1, kt,   1);
        P2BODY(kB0, kB1, kA0, kA1, kt+1, 1);
    }
    P2BODY(kA0, kA1, kB0, kB1, 30, 1);
    P2BODY(kB0, kB1, kA0, kA1, 31, 0);

#pragma unroll
    for (int j = 0; j < 4; ++j)
#pragma unroll
        for (int r = 0; r < 4; ++r) {
            int row = q0 + lg*4 + r;
            int col = h*DK + j*16 + lr;
            C16[(size_t)(b*SEQ + row) * DMODEL + col] = (f16)cacc[j][r];
        }
}

// ---------------------------------------------------------------------------
extern "C" void kernel_launch(void* const* d_in, const int* in_sizes, int n_in,
                              void* d_out, int out_size, void* d_ws, size_t ws_size,
                              hipStream_t stream)
{
    const float* query = (const float*)d_in[0];
    const float* key   = (const float*)d_in[1];
    const float* value = (const float*)d_in[2];
    const float* Wq    = (const float*)d_in[3];
    const float* bq    = (const float*)d_in[4];
    const float* Wk    = (const float*)d_in[5];
    const float* bk    = (const float*)d_in[6];
    const float* Wv    = (const float*)d_in[7];
    const float* bv    = (const float*)d_in[8];
    const float* Wo    = (const float*)d_in[9];
    const float* bo    = (const float*)d_in[10];

    float* out  = (float*)d_out;                    // (B,S,DMODEL) fp32
    float* attn = (float*)d_out + OUT0_ELEMS;       // (B,H,S,S)   fp32

    // f16 workspace, 56 MB. Vt16/C16 overlay Xq/Xk (dead after their projs).
    f16* Q16  = (f16*)d_ws;
    f16* K16  = Q16  + (size_t)MROWS * DMODEL;
    f16* V16  = K16  + (size_t)MROWS * DMODEL;
    f16* Wq16 = V16  + (size_t)MROWS * DMODEL;
    f16* Wk16 = Wq16 + (size_t)DMODEL * DMODEL;
    f16* Wv16 = Wk16 + (size_t)DMODEL * DMODEL;
    f16* Wo16 = Wv16 + (size_t)DMODEL * DMODEL;
    f16* Xq   = Wo16 + (size_t)DMODEL * DMODEL;
    f16* Xk   = Xq   + (size_t)MROWS * DMODEL;
    f16* Xv   = Xk   + (size_t)MROWS * DMODEL;
    f16* Vt16 = Xq;                                 // reuse after Q projection
    f16* C16  = Xk;                                 // reuse after K projection

    dim3 t256(256), t512(512);
    hipLaunchKernelGGL(cast_f32_f16, dim3(1024), t256, 0, stream, Wq, Wq16);
    hipLaunchKernelGGL(cast_f32_f16, dim3(1024), t256, 0, stream, Wk, Wk16);
    hipLaunchKernelGGL(cast_f32_f16, dim3(1024), t256, 0, stream, Wv, Wv16);
    hipLaunchKernelGGL(cast_f32_f16, dim3(1024), t256, 0, stream, Wo, Wo16);
    hipLaunchKernelGGL(cast_f32_f16, dim3(4096), t256, 0, stream, query, Xq);
    hipLaunchKernelGGL(cast_f32_f16, dim3(4096), t256, 0, stream, key,   Xk);
    hipLaunchKernelGGL(cast_f32_f16, dim3(4096), t256, 0, stream, value, Xv);

    dim3 gProj(MROWS / 128, DMODEL / 128);          // (32, 8)
    hipLaunchKernelGGL((gemm128<f16>), gProj, t512, 0, stream, Xq, Wq16, bq, Q16);
    hipLaunchKernelGGL((gemm128<f16>), gProj, t512, 0, stream, Xk, Wk16, bk, K16);
    hipLaunchKernelGGL((gemm128<f16>), gProj, t512, 0, stream, Xv, Wv16, bv, V16);

    dim3 gTr(MROWS / 64, DMODEL / 64);              // (64, 16)
    hipLaunchKernelGGL(transpose_v, gTr, t256, 0, stream, V16, Vt16);

    dim3 gAttn(BATCH * NHEADS, SEQ / 64);           // (32, 32)
    hipLaunchKernelGGL(attn_kernel, gAttn, t256, 0, stream, Q16, K16, Vt16, attn, C16);

    hipLaunchKernelGGL((gemm128<float>), gProj, t512, 0, stream, C16, Wo16, bo, out);
}